// Round 1
// baseline (488.237 us; speedup 1.0000x reference)
//
#include <hip/hip_runtime.h>

using u16 = unsigned short;
typedef __bf16 bf16x8 __attribute__((ext_vector_type(8)));
typedef float floatx4 __attribute__((ext_vector_type(4)));

__device__ __forceinline__ u16 f2bf(float f) {
  union { float f; unsigned u; } c; c.f = f;
  unsigned u = c.u;
  u += 0x7fffu + ((u >> 16) & 1u);   // round-to-nearest-even
  return (u16)(u >> 16);
}

__device__ __forceinline__ void st_out(float* p, float v) { *p = v; }
__device__ __forceinline__ void st_out(u16* p, float v) { *p = f2bf(v); }

__device__ __forceinline__ void load16(const u16* g, u16* l) {
  __builtin_amdgcn_global_load_lds(
      (const __attribute__((address_space(1))) void*)g,
      (__attribute__((address_space(3))) void*)l, 16, 0, 0);
}

#define TILE 128
#define BK 32

// C[M,N] = A[M,K] @ Bt[N,K]^T   (all inputs bf16, fp32 accumulate)
// MODE 0: plain   MODE 1: causal tile skip (bx>by)   MODE 2: causal K-trim
template<typename OutT, int MODE>
__global__ __launch_bounds__(256, 2)
void gemm_bt(const u16* __restrict__ A, int lda, long sA,
             const u16* __restrict__ Bt, int ldb, long sB,
             OutT* __restrict__ C, int ldc, long sC, int K)
{
  int bx = blockIdx.x, by = blockIdx.y, bz = blockIdx.z;
  if (MODE == 1 && bx > by) return;
  int kmax = K;
  if (MODE == 2) { int t = (by + 1) * TILE; if (t < kmax) kmax = t; }

  __shared__ u16 As[TILE * BK];
  __shared__ u16 Bs[TILE * BK];

  const u16* Ab = A + bz * sA + (long)by * TILE * lda;
  const u16* Bb = Bt + bz * sB + (long)bx * TILE * ldb;

  int tid = threadIdx.x;
  int lane = tid & 63;
  int wm = ((tid >> 7) & 1) * 64;   // wave row offset in tile
  int wn = ((tid >> 6) & 1) * 64;   // wave col offset in tile

  // staging: chunk c covers LDS bytes [c*16, c*16+16); row=c>>2, koff=(c&3)*8
  int c0 = tid, c1 = tid + 256;
  int r0 = c0 >> 2, kc0 = (c0 & 3) * 8;
  int r1 = c1 >> 2, kc1 = (c1 & 3) * 8;

  floatx4 acc[4][4] = {};

  int arow = wm + (lane & 15);
  int brow = wn + (lane & 15);
  int koff = (lane >> 4) * 8;

  for (int k0 = 0; k0 < kmax; k0 += BK) {
    __syncthreads();
    load16(Ab + (long)r0 * lda + k0 + kc0, &As[c0 * 8]);
    load16(Ab + (long)r1 * lda + k0 + kc1, &As[c1 * 8]);
    load16(Bb + (long)r0 * ldb + k0 + kc0, &Bs[c0 * 8]);
    load16(Bb + (long)r1 * ldb + k0 + kc1, &Bs[c1 * 8]);
    __builtin_amdgcn_s_waitcnt(0);
    __syncthreads();

    bf16x8 a[4], b[4];
#pragma unroll
    for (int i = 0; i < 4; i++)
      a[i] = *(const bf16x8*)&As[(arow + i * 16) * BK + koff];
#pragma unroll
    for (int j = 0; j < 4; j++)
      b[j] = *(const bf16x8*)&Bs[(brow + j * 16) * BK + koff];
#pragma unroll
    for (int i = 0; i < 4; i++)
#pragma unroll
      for (int j = 0; j < 4; j++)
        acc[i][j] = __builtin_amdgcn_mfma_f32_16x16x32_bf16(a[i], b[j], acc[i][j], 0, 0, 0);
  }

  // epilogue: C/D layout col=lane&15, row=(lane>>4)*4+reg  [m89-verified]
  OutT* Cb = C + bz * sC;
  int colbase = bx * TILE + wn + (lane & 15);
  int rowbase = by * TILE + wm + ((lane >> 4) << 2);
#pragma unroll
  for (int i = 0; i < 4; i++)
#pragma unroll
    for (int j = 0; j < 4; j++) {
      int col = colbase + j * 16;
#pragma unroll
      for (int r = 0; r < 4; r++) {
        int row = rowbase + i * 16 + r;
        st_out(&Cb[(long)row * ldc + col], acc[i][j][r]);
      }
    }
}

// x fp32 -> bf16, 4 elems/thread
__global__ __launch_bounds__(256)
void cvt_x(const float4* __restrict__ x, u16* __restrict__ o, int n4)
{
  int i = blockIdx.x * 256 + threadIdx.x;
  if (i >= n4) return;
  float4 v = x[i];
  ushort4 r;
  r.x = f2bf(v.x); r.y = f2bf(v.y); r.z = f2bf(v.z); r.w = f2bf(v.w);
  *(ushort4*)(o + (long)i * 4) = r;
}

// W (d_in x d_out) fp32 -> W^T (d_out x d_in) bf16, LDS tiled; z selects matrix
__global__ __launch_bounds__(256)
void cvt_w(const float* __restrict__ Wq, const float* __restrict__ Wk,
           const float* __restrict__ Wv, u16* __restrict__ WT)
{
  const int D = 1024;
  int z = blockIdx.z;
  const float* W = (z == 0) ? Wq : (z == 1) ? Wk : Wv;
  u16* O = WT + (long)z * D * D;
  __shared__ float t[64][65];
  int tid = threadIdx.x;
  int c = tid & 63, r = tid >> 6;       // r = 0..3
  int e0 = blockIdx.x * 64, d0 = blockIdx.y * 64;
  for (int rr = r; rr < 64; rr += 4)
    t[rr][c] = W[(long)(d0 + rr) * D + e0 + c];
  __syncthreads();
  for (int rr = r; rr < 64; rr += 4)
    O[(long)(e0 + rr) * D + d0 + c] = f2bf(t[c][rr]);
}

// per-row causal softmax; reads S fp32, writes P bf16 in-place (row pitch 4096 u16)
__global__ __launch_bounds__(256)
void softmax_causal(float* __restrict__ S, float scale)
{
  const int T = 2048;
  int row = blockIdx.x & (T - 1);
  int bi  = blockIdx.x >> 11;
  float* Srow = S + ((long)bi * T + row) * T;
  u16* Prow = (u16*)Srow;
  int n = row + 1;                      // valid entries (k <= row)
  int nw = ((row >> 7) + 1) << 7;       // zero-fill to 128-tile boundary

  __shared__ float buf[T];
  __shared__ float red[8];
  int tid = threadIdx.x, lane = tid & 63, wid = tid >> 6;

  float lmax = -3.0e38f;
  for (int i = tid; i < n; i += 256) {
    float v = Srow[i] * scale;
    buf[i] = v;
    lmax = fmaxf(lmax, v);
  }
#pragma unroll
  for (int o = 32; o > 0; o >>= 1) lmax = fmaxf(lmax, __shfl_down(lmax, o, 64));
  if (lane == 0) red[wid] = lmax;
  __syncthreads();
  float m = fmaxf(fmaxf(red[0], red[1]), fmaxf(red[2], red[3]));

  float lsum = 0.f;
  for (int i = tid; i < n; i += 256) {
    float e = __expf(buf[i] - m);
    buf[i] = e;
    lsum += e;
  }
#pragma unroll
  for (int o = 32; o > 0; o >>= 1) lsum += __shfl_down(lsum, o, 64);
  if (lane == 0) red[4 + wid] = lsum;
  __syncthreads();
  float inv = 1.0f / (red[4] + red[5] + red[6] + red[7]);

  for (int i = tid; i < n; i += 256) Prow[i] = f2bf(buf[i] * inv);
  for (int i = n + tid; i < nw; i += 256) Prow[i] = 0;
}

extern "C" void kernel_launch(void* const* d_in, const int* in_sizes, int n_in,
                              void* d_out, int out_size, void* d_ws, size_t ws_size,
                              hipStream_t stream)
{
  const int B = 8, T = 2048, D = 1024;
  const float* x  = (const float*)d_in[0];
  const float* Wq = (const float*)d_in[1];
  const float* Wk = (const float*)d_in[2];
  const float* Wv = (const float*)d_in[3];
  float* out = (float*)d_out;
  char* ws = (char*)d_ws;

  // workspace layout (bytes)
  const size_t OFF_X  = 0;            // x bf16: 16384x1024      (32 MB)
  const size_t OFF_W  = 33554432;     // WqT|WkT|WvT bf16        ( 6 MB)
  const size_t OFF_Q  = 39845888;     // Q bf16: 16384x1024      (32 MB)
  const size_t OFF_K  = 73400320;     // K bf16                  (32 MB)
  const size_t OFF_VT = 106954752;    // V^T bf16: 1024x16384    (32 MB)
  const size_t OFF_S  = 140509184;    // S fp32: NB x 2048x2048  (16 MB/batch)

  u16* xb = (u16*)(ws + OFF_X);
  u16* WT = (u16*)(ws + OFF_W);
  u16* Qb = (u16*)(ws + OFF_Q);
  u16* Kb = (u16*)(ws + OFF_K);
  u16* VT = (u16*)(ws + OFF_VT);
  float* S = (float*)(ws + OFF_S);

  int NB = 8;   // batches per chunk; shrink if workspace is small (deterministic)
  while (NB > 1 && OFF_S + (size_t)NB * T * T * 4 > ws_size) NB >>= 1;

  cvt_x<<<(B * T * D / 4 + 255) / 256, 256, 0, stream>>>((const float4*)x, xb, B * T * D / 4);
  cvt_w<<<dim3(16, 16, 3), 256, 0, stream>>>(Wq, Wk, Wv, WT);

  // Q = x@Wq, K = x@Wk (z selects weight/output)
  gemm_bt<u16, 0><<<dim3(D / TILE, B * T / TILE, 2), 256, 0, stream>>>(
      xb, D, 0L, WT, D, (long)D * D, Qb, D, (long)B * T * D, D);
  // V^T = Wv^T @ x^T  (A = WvT row-major, Bt = x row-major)
  gemm_bt<u16, 0><<<dim3(B * T / TILE, D / TILE, 1), 256, 0, stream>>>(
      WT + 2L * D * D, D, 0L, xb, D, 0L, VT, B * T, 0L, D);

  for (int b0 = 0; b0 < B; b0 += NB) {
    // S = Q K^T (raw, fp32), skip above-diagonal tiles
    gemm_bt<float, 1><<<dim3(T / TILE, T / TILE, NB), 256, 0, stream>>>(
        Qb + (long)b0 * T * D, D, (long)T * D,
        Kb + (long)b0 * T * D, D, (long)T * D,
        S, T, (long)T * T, D);
    // softmax rows, write P bf16 in-place (pitch 2T u16)
    softmax_causal<<<NB * T, 256, 0, stream>>>(S, 0.03125f);
    // O = P V  via  Bt = V^T columns of this batch; K-loop trimmed causally
    gemm_bt<float, 2><<<dim3(D / TILE, T / TILE, NB), 256, 0, stream>>>(
        (const u16*)S, 2 * T, (long)T * 2 * T,
        VT + (long)b0 * T, B * T, (long)T,
        out + (long)b0 * T * D, D, (long)T * D, T);
  }
}

// Round 2
// 448.038 us; speedup vs baseline: 1.0897x; 1.0897x over previous
//
#include <hip/hip_runtime.h>

using u16 = unsigned short;
typedef __bf16 bf16x8 __attribute__((ext_vector_type(8)));
typedef float floatx4 __attribute__((ext_vector_type(4)));

__device__ __forceinline__ u16 f2bf(float f) {
  union { float f; unsigned u; } c; c.f = f;
  unsigned u = c.u;
  u += 0x7fffu + ((u >> 16) & 1u);   // round-to-nearest-even
  return (u16)(u >> 16);
}

__device__ __forceinline__ void st_out(float* p, float v) { *p = v; }
__device__ __forceinline__ void st_out(u16* p, float v) { *p = f2bf(v); }

__device__ __forceinline__ void load16(const u16* g, u16* l) {
  __builtin_amdgcn_global_load_lds(
      (const __attribute__((address_space(1))) void*)g,
      (__attribute__((address_space(3))) void*)l, 16, 0, 0);
}

#define TILE 128
#define BK 32
// bank-conflict swizzle key: rows r..r+15 spread kpart chunks over all banks
#define KEY(r) ((((r) & 3) ^ (((r) >> 2) & 3)))

// C[M,N] = A[M,K] @ Bt[N,K]^T   (all inputs bf16, fp32 accumulate)
// MODE 0: plain   MODE 1: causal tile skip (bx>by)   MODE 2: causal K-trim
template<typename OutT, int MODE>
__global__ __launch_bounds__(256, 2)
void gemm_bt(const u16* __restrict__ A, int lda, long sA,
             const u16* __restrict__ Bt, int ldb, long sB,
             OutT* __restrict__ C, int ldc, long sC, int K)
{
  int bx = blockIdx.x, by = blockIdx.y, bz = blockIdx.z;
  if (MODE == 1 && bx > by) return;
  int kmax = K;
  if (MODE == 2) { int t = (by + 1) * TILE; if (t < kmax) kmax = t; }

  __shared__ u16 As[TILE * BK];
  __shared__ u16 Bs[TILE * BK];

  const u16* Ab = A + bz * sA + (long)by * TILE * lda;
  const u16* Bb = Bt + bz * sB + (long)bx * TILE * ldb;

  int tid = threadIdx.x;
  int lane = tid & 63;
  int wm = ((tid >> 7) & 1) * 64;   // wave row offset in tile
  int wn = ((tid >> 6) & 1) * 64;   // wave col offset in tile

  // staging: LDS chunk c holds global chunk (row=c>>2, kpart=(c&3)^KEY(row));
  // the xor permutes 16B chunks WITHIN each row's 64B segment (coalescing kept)
  int c0 = tid, c1 = tid + 256;
  int r0 = c0 >> 2, p0 = ((c0 & 3) ^ KEY(r0)) * 8;
  int r1 = c1 >> 2, p1 = ((c1 & 3) ^ KEY(r1)) * 8;

  floatx4 acc[4][4] = {};

  int arow = wm + (lane & 15);
  int brow = wn + (lane & 15);
  int q = lane >> 4;                // kpart selector for fragment reads

  for (int k0 = 0; k0 < kmax; k0 += BK) {
    __syncthreads();
    load16(Ab + (long)r0 * lda + k0 + p0, &As[c0 * 8]);
    load16(Ab + (long)r1 * lda + k0 + p1, &As[c1 * 8]);
    load16(Bb + (long)r0 * ldb + k0 + p0, &Bs[c0 * 8]);
    load16(Bb + (long)r1 * ldb + k0 + p1, &Bs[c1 * 8]);
    __builtin_amdgcn_s_waitcnt(0);
    __syncthreads();

    bf16x8 a[4], b[4];
#pragma unroll
    for (int i = 0; i < 4; i++) {
      int r = arow + i * 16;
      a[i] = *(const bf16x8*)&As[((r << 2) | (q ^ KEY(r))) * 8];
    }
#pragma unroll
    for (int j = 0; j < 4; j++) {
      int r = brow + j * 16;
      b[j] = *(const bf16x8*)&Bs[((r << 2) | (q ^ KEY(r))) * 8];
    }
#pragma unroll
    for (int i = 0; i < 4; i++)
#pragma unroll
      for (int j = 0; j < 4; j++)
        acc[i][j] = __builtin_amdgcn_mfma_f32_16x16x32_bf16(a[i], b[j], acc[i][j], 0, 0, 0);
  }

  // epilogue: C/D layout col=lane&15, row=(lane>>4)*4+reg  [m89-verified]
  OutT* Cb = C + bz * sC;
  int colbase = bx * TILE + wn + (lane & 15);
  int rowbase = by * TILE + wm + ((lane >> 4) << 2);
#pragma unroll
  for (int i = 0; i < 4; i++)
#pragma unroll
    for (int j = 0; j < 4; j++) {
      int col = colbase + j * 16;
#pragma unroll
      for (int r = 0; r < 4; r++) {
        int row = rowbase + i * 16 + r;
        st_out(&Cb[(long)row * ldc + col], acc[i][j][r]);
      }
    }
}

// fp32 -> bf16, 4 elems/thread (also used for row-major weight converts)
__global__ __launch_bounds__(256)
void cvt_x(const float4* __restrict__ x, u16* __restrict__ o, int n4)
{
  int i = blockIdx.x * 256 + threadIdx.x;
  if (i >= n4) return;
  float4 v = x[i];
  ushort4 r;
  r.x = f2bf(v.x); r.y = f2bf(v.y); r.z = f2bf(v.z); r.w = f2bf(v.w);
  *(ushort4*)(o + (long)i * 4) = r;
}

// W (d_in x d_out) fp32 -> W^T (d_out x d_in) bf16, LDS tiled
__global__ __launch_bounds__(256)
void cvt_w(const float* __restrict__ W, u16* __restrict__ O)
{
  const int D = 1024;
  __shared__ float t[64][65];
  int tid = threadIdx.x;
  int c = tid & 63, r = tid >> 6;       // r = 0..3
  int e0 = blockIdx.x * 64, d0 = blockIdx.y * 64;
  for (int rr = r; rr < 64; rr += 4)
    t[rr][c] = W[(long)(d0 + rr) * D + e0 + c];
  __syncthreads();
  for (int rr = r; rr < 64; rr += 4)
    O[(long)(e0 + rr) * D + d0 + c] = f2bf(t[c][rr]);
}

// per-row causal softmax; reads S fp32, writes P bf16 in-place (row pitch 4096 u16)
__global__ __launch_bounds__(256)
void softmax_causal(float* __restrict__ S, float scale)
{
  const int T = 2048;
  int row = blockIdx.x & (T - 1);
  int bi  = blockIdx.x >> 11;
  float* Srow = S + ((long)bi * T + row) * T;
  u16* Prow = (u16*)Srow;
  int n = row + 1;                      // valid entries (k <= row)
  int nw = ((row >> 7) + 1) << 7;       // zero-fill to 128-tile boundary

  __shared__ float buf[T];
  __shared__ float red[8];
  int tid = threadIdx.x, lane = tid & 63, wid = tid >> 6;

  float lmax = -3.0e38f;
  for (int i = tid; i < n; i += 256) {
    float v = Srow[i] * scale;
    buf[i] = v;
    lmax = fmaxf(lmax, v);
  }
#pragma unroll
  for (int o = 32; o > 0; o >>= 1) lmax = fmaxf(lmax, __shfl_down(lmax, o, 64));
  if (lane == 0) red[wid] = lmax;
  __syncthreads();
  float m = fmaxf(fmaxf(red[0], red[1]), fmaxf(red[2], red[3]));

  float lsum = 0.f;
  for (int i = tid; i < n; i += 256) {
    float e = __expf(buf[i] - m);
    buf[i] = e;
    lsum += e;
  }
#pragma unroll
  for (int o = 32; o > 0; o >>= 1) lsum += __shfl_down(lsum, o, 64);
  if (lane == 0) red[4 + wid] = lsum;
  __syncthreads();
  float inv = 1.0f / (red[4] + red[5] + red[6] + red[7]);

  for (int i = tid; i < n; i += 256) Prow[i] = f2bf(buf[i] * inv);
  for (int i = n + tid; i < nw; i += 256) Prow[i] = 0;
}

extern "C" void kernel_launch(void* const* d_in, const int* in_sizes, int n_in,
                              void* d_out, int out_size, void* d_ws, size_t ws_size,
                              hipStream_t stream)
{
  const int B = 8, T = 2048, D = 1024;
  const float* x  = (const float*)d_in[0];
  const float* Wq = (const float*)d_in[1];
  const float* Wk = (const float*)d_in[2];
  const float* Wv = (const float*)d_in[3];
  float* out = (float*)d_out;
  char* ws = (char*)d_ws;

  // workspace layout (bytes)
  const size_t OFF_X   = 0;                       // x bf16: 16384x1024   (32 MB)
  const size_t OFF_WQ  = 32ul << 20;              // Wq bf16 row-major    ( 2 MB)
  const size_t OFF_WK  = 34ul << 20;              // Wk bf16 row-major    ( 2 MB)
  const size_t OFF_WVT = 36ul << 20;              // Wv^T bf16            ( 2 MB)
  const size_t OFF_NT  = 38ul << 20;              // N^T = Wk Wq^T bf16   ( 2 MB)
  const size_t OFF_Y   = 40ul << 20;              // Y = x(WqWk^T) bf16   (32 MB)
  const size_t OFF_VT  = 72ul << 20;              // V^T bf16: 1024x16384 (32 MB)
  const size_t OFF_S   = 104ul << 20;             // S fp32: NB x 2048^2  (16 MB/batch)

  u16* xb  = (u16*)(ws + OFF_X);
  u16* Wqb = (u16*)(ws + OFF_WQ);
  u16* Wkb = (u16*)(ws + OFF_WK);
  u16* WvT = (u16*)(ws + OFF_WVT);
  u16* NT  = (u16*)(ws + OFF_NT);
  u16* Yb  = (u16*)(ws + OFF_Y);
  u16* VT  = (u16*)(ws + OFF_VT);
  float* S = (float*)(ws + OFF_S);

  int NB = 8;   // batches per chunk; shrink if workspace is small (deterministic)
  while (NB > 1 && OFF_S + (size_t)NB * T * T * 4 > ws_size) NB >>= 1;

  cvt_x<<<(B * T * D / 4 + 255) / 256, 256, 0, stream>>>((const float4*)x, xb, B * T * D / 4);
  cvt_x<<<(D * D / 4 + 255) / 256, 256, 0, stream>>>((const float4*)Wq, Wqb, D * D / 4);
  cvt_x<<<(D * D / 4 + 255) / 256, 256, 0, stream>>>((const float4*)Wk, Wkb, D * D / 4);
  cvt_w<<<dim3(16, 16), 256, 0, stream>>>(Wv, WvT);

  // N^T[d',d] = sum_e Wk[d',e] Wq[d,e]   (so S = x Wq Wk^T x^T = (x N) x^T)
  gemm_bt<u16, 0><<<dim3(D / TILE, D / TILE, 1), 256, 0, stream>>>(
      Wkb, D, 0L, Wqb, D, 0L, NT, D, 0L, D);
  // Y[t,d'] = sum_d x[t,d] N[d,d'] = sum_d x[t,d] NT[d',d]
  gemm_bt<u16, 0><<<dim3(D / TILE, B * T / TILE, 1), 256, 0, stream>>>(
      xb, D, 0L, NT, D, 0L, Yb, D, 0L, D);
  // V^T = Wv^T @ x^T  (A = WvT row-major, Bt = x row-major)
  gemm_bt<u16, 0><<<dim3(B * T / TILE, D / TILE, 1), 256, 0, stream>>>(
      WvT, D, 0L, xb, D, 0L, VT, B * T, 0L, D);

  for (int b0 = 0; b0 < B; b0 += NB) {
    // S = Y x^T (raw scores, fp32), skip above-diagonal tiles
    gemm_bt<float, 1><<<dim3(T / TILE, T / TILE, NB), 256, 0, stream>>>(
        Yb + (long)b0 * T * D, D, (long)T * D,
        xb + (long)b0 * T * D, D, (long)T * D,
        S, T, (long)T * T, D);
    // softmax rows, write P bf16 in-place (pitch 2T u16)
    softmax_causal<<<NB * T, 256, 0, stream>>>(S, 0.03125f);
    // O = P V  via  Bt = V^T columns of this batch; K-loop trimmed causally
    gemm_bt<float, 2><<<dim3(D / TILE, T / TILE, NB), 256, 0, stream>>>(
        (const u16*)S, 2 * T, (long)T * 2 * T,
        VT + (long)b0 * T, B * T, (long)T,
        out + (long)b0 * T * D, D, (long)T * D, T);
  }
}

// Round 3
// 392.735 us; speedup vs baseline: 1.2432x; 1.1408x over previous
//
#include <hip/hip_runtime.h>

using u16 = unsigned short;
typedef __bf16 bf16x8 __attribute__((ext_vector_type(8)));
typedef float floatx4 __attribute__((ext_vector_type(4)));

__device__ __forceinline__ u16 f2bf(float f) {
  union { float f; unsigned u; } c; c.f = f;
  unsigned u = c.u;
  u += 0x7fffu + ((u >> 16) & 1u);   // round-to-nearest-even
  return (u16)(u >> 16);
}

__device__ __forceinline__ void st_out(float* p, float v) { *p = v; }
__device__ __forceinline__ void st_out(u16* p, float v) { *p = f2bf(v); }

__device__ __forceinline__ void load16(const u16* g, u16* l) {
  __builtin_amdgcn_global_load_lds(
      (const __attribute__((address_space(1))) void*)g,
      (__attribute__((address_space(3))) void*)l, 16, 0, 0);
}

#define TILE 128
#define BK 64

// Core 128x128 tile GEMM, BK=64: C = A[M,K] @ Bt[N,K]^T, bf16 in, fp32 acc.
// LDS layout: row r holds its 8 16B-chunks XOR-permuted (slot = m ^ (r&7)) so
// quarter-wave fragment reads hit all 8 bank groups 2x (free, m136).
template<typename OutT>
__device__ __forceinline__ void gemm_core(
    const u16* __restrict__ A, int lda, long sA,
    const u16* __restrict__ Bt, int ldb, long sB,
    OutT* __restrict__ C, int ldc, long sC,
    int kmax, int bx, int by, int bz, int tid)
{
  __shared__ u16 As[TILE * BK];
  __shared__ u16 Bs[TILE * BK];

  const u16* Ab = A + bz * sA + (long)by * TILE * lda;
  const u16* Bb = Bt + bz * sB + (long)bx * TILE * ldb;

  int lane = tid & 63;
  int wm = ((tid >> 7) & 1) * 64;
  int wn = ((tid >> 6) & 1) * 64;

  floatx4 acc[4][4] = {};
  int arow = wm + (lane & 15);
  int brow = wn + (lane & 15);
  int q = lane >> 4;

  for (int k0 = 0; k0 < kmax; k0 += BK) {
    __syncthreads();
#pragma unroll
    for (int h = 0; h < 4; h++) {
      int cc = tid + h * 256;
      int row = cc >> 3, gm = (cc & 7) ^ (row & 7);
      load16(Ab + (long)row * lda + k0 + gm * 8, &As[cc * 8]);
    }
#pragma unroll
    for (int h = 0; h < 4; h++) {
      int cc = tid + h * 256;
      int row = cc >> 3, gm = (cc & 7) ^ (row & 7);
      load16(Bb + (long)row * ldb + k0 + gm * 8, &Bs[cc * 8]);
    }
    __builtin_amdgcn_s_waitcnt(0);
    __syncthreads();

#pragma unroll
    for (int kp = 0; kp < 2; kp++) {
      bf16x8 a[4], b[4];
#pragma unroll
      for (int i = 0; i < 4; i++) {
        int r = arow + i * 16;
        a[i] = *(const bf16x8*)&As[(r * 8 + ((kp * 4 + q) ^ (r & 7))) * 8];
      }
#pragma unroll
      for (int j = 0; j < 4; j++) {
        int r = brow + j * 16;
        b[j] = *(const bf16x8*)&Bs[(r * 8 + ((kp * 4 + q) ^ (r & 7))) * 8];
      }
#pragma unroll
      for (int i = 0; i < 4; i++)
#pragma unroll
        for (int j = 0; j < 4; j++)
          acc[i][j] = __builtin_amdgcn_mfma_f32_16x16x32_bf16(a[i], b[j], acc[i][j], 0, 0, 0);
    }
  }

  // epilogue: C/D layout col=lane&15, row=(lane>>4)*4+reg  [m89-verified]
  OutT* Cb = C + bz * sC;
  int colbase = bx * TILE + wn + (lane & 15);
  int rowbase = by * TILE + wm + ((lane >> 4) << 2);
#pragma unroll
  for (int i = 0; i < 4; i++)
#pragma unroll
    for (int j = 0; j < 4; j++) {
      int col = colbase + j * 16;
#pragma unroll
      for (int r = 0; r < 4; r++)
        st_out(&Cb[(long)(rowbase + i * 16 + r) * ldc + col], acc[i][j][r]);
    }
}

// Rectangular GEMM, 1D grid with XCD-contiguous remap:
// L%8 = XCD (round-robin heuristic); each XCD gets a contiguous tile range.
template<typename OutT>
__global__ __launch_bounds__(256, 2)
void gemm_rect(const u16* __restrict__ A, int lda, long sA,
               const u16* __restrict__ Bt, int ldb, long sB,
               OutT* __restrict__ C, int ldc, long sC, int K,
               int l2gx, int nO8s)
{
  int L = blockIdx.x;
  int t = ((L & 7) << nO8s) | (L >> 3);
  int bx = t & ((1 << l2gx) - 1), by = t >> l2gx;
  gemm_core<OutT>(A, lda, sA, Bt, ldb, sB, C, ldc, sC, K, bx, by, blockIdx.y, threadIdx.x);
}

// Causal S = Y @ x^T: enumerate only the 136 lower-triangle tiles per batch,
// XCD-grouped (17 contiguous triangle slots per XCD), fp32 out.
__global__ __launch_bounds__(256, 2)
void gemm_tri(const u16* __restrict__ A, int lda, long sA,
              const u16* __restrict__ Bt, int ldb, long sB,
              float* __restrict__ C, int ldc, long sC, int K)
{
  int tp = blockIdx.x;                       // 0..135
  int t = (tp & 7) * 17 + (tp >> 3);         // XCD j -> slots [17j,17j+17)
  int r = (int)((sqrtf(8.f * t + 1.f) - 1.f) * 0.5f);
  while ((r + 1) * (r + 2) / 2 <= t) ++r;
  while (r * (r + 1) / 2 > t) --r;
  int c = t - r * (r + 1) / 2;               // c <= r
  gemm_core<float>(A, lda, sA, Bt, ldb, sB, C, ldc, sC, K, c, r, blockIdx.y, threadIdx.x);
}

// O = P @ V via VT; causal K-trim. XCD j handles by in {j, 15-j} (equal work:
// (j+1)+(16-j)=17 K-tiles), with all 8 bx per row on the same XCD (P-strip reuse).
__global__ __launch_bounds__(256, 2)
void gemm_opv(const u16* __restrict__ P, int lda, long sA,
              const u16* __restrict__ VT, int ldb, long sB,
              float* __restrict__ C, int ldc, long sC)
{
  int L = blockIdx.x;                        // 0..127
  int j = L & 7, s = L >> 3;
  int by = (s < 8) ? j : 15 - j;
  int bx = s & 7;
  gemm_core<float>(P, lda, sA, VT, ldb, sB, C, ldc, sC,
                   (by + 1) * TILE, bx, by, blockIdx.y, threadIdx.x);
}

// fp32 -> bf16, 4 elems/thread
__global__ __launch_bounds__(256)
void cvt_x(const float4* __restrict__ x, u16* __restrict__ o, int n4)
{
  int i = blockIdx.x * 256 + threadIdx.x;
  if (i >= n4) return;
  float4 v = x[i];
  ushort4 r;
  r.x = f2bf(v.x); r.y = f2bf(v.y); r.z = f2bf(v.z); r.w = f2bf(v.w);
  *(ushort4*)(o + (long)i * 4) = r;
}

// W (d_in x d_out) fp32 -> W^T (d_out x d_in) bf16, LDS tiled
__global__ __launch_bounds__(256)
void cvt_w(const float* __restrict__ W, u16* __restrict__ O)
{
  const int D = 1024;
  __shared__ float t[64][65];
  int tid = threadIdx.x;
  int c = tid & 63, r = tid >> 6;
  int e0 = blockIdx.x * 64, d0 = blockIdx.y * 64;
  for (int rr = r; rr < 64; rr += 4)
    t[rr][c] = W[(long)(d0 + rr) * D + e0 + c];
  __syncthreads();
  for (int rr = r; rr < 64; rr += 4)
    O[(long)(e0 + rr) * D + d0 + c] = f2bf(t[c][rr]);
}

// per-row causal softmax; reads S fp32, writes P bf16 in-place (row pitch 4096 u16)
__global__ __launch_bounds__(256)
void softmax_causal(float* __restrict__ S, float scale)
{
  const int T = 2048;
  int row = blockIdx.x & (T - 1);
  int bi  = blockIdx.x >> 11;
  float* Srow = S + ((long)bi * T + row) * T;
  u16* Prow = (u16*)Srow;
  int n = row + 1;
  int nw = ((row >> 7) + 1) << 7;

  __shared__ float buf[T];
  __shared__ float red[8];
  int tid = threadIdx.x, lane = tid & 63, wid = tid >> 6;

  float lmax = -3.0e38f;
  for (int i = tid; i < n; i += 256) {
    float v = Srow[i] * scale;
    buf[i] = v;
    lmax = fmaxf(lmax, v);
  }
#pragma unroll
  for (int o = 32; o > 0; o >>= 1) lmax = fmaxf(lmax, __shfl_down(lmax, o, 64));
  if (lane == 0) red[wid] = lmax;
  __syncthreads();
  float m = fmaxf(fmaxf(red[0], red[1]), fmaxf(red[2], red[3]));

  float lsum = 0.f;
  for (int i = tid; i < n; i += 256) {
    float e = __expf(buf[i] - m);
    buf[i] = e;
    lsum += e;
  }
#pragma unroll
  for (int o = 32; o > 0; o >>= 1) lsum += __shfl_down(lsum, o, 64);
  if (lane == 0) red[4 + wid] = lsum;
  __syncthreads();
  float inv = 1.0f / (red[4] + red[5] + red[6] + red[7]);

  for (int i = tid; i < n; i += 256) Prow[i] = f2bf(buf[i] * inv);
  for (int i = n + tid; i < nw; i += 256) Prow[i] = 0;
}

extern "C" void kernel_launch(void* const* d_in, const int* in_sizes, int n_in,
                              void* d_out, int out_size, void* d_ws, size_t ws_size,
                              hipStream_t stream)
{
  const int B = 8, T = 2048, D = 1024;
  const float* x  = (const float*)d_in[0];
  const float* Wq = (const float*)d_in[1];
  const float* Wk = (const float*)d_in[2];
  const float* Wv = (const float*)d_in[3];
  float* out = (float*)d_out;
  char* ws = (char*)d_ws;

  const size_t OFF_X   = 0;                       // x bf16: 16384x1024   (32 MB)
  const size_t OFF_WQ  = 32ul << 20;              // Wq bf16 row-major    ( 2 MB)
  const size_t OFF_WK  = 34ul << 20;              // Wk bf16 row-major    ( 2 MB)
  const size_t OFF_WVT = 36ul << 20;              // Wv^T bf16            ( 2 MB)
  const size_t OFF_NT  = 38ul << 20;              // N^T = Wk Wq^T bf16   ( 2 MB)
  const size_t OFF_Y   = 40ul << 20;              // Y = x(WqWk^T) bf16   (32 MB)
  const size_t OFF_VT  = 72ul << 20;              // V^T bf16: 1024x16384 (32 MB)
  const size_t OFF_S   = 104ul << 20;             // S fp32: NB x 2048^2  (16 MB/batch)

  u16* xb  = (u16*)(ws + OFF_X);
  u16* Wqb = (u16*)(ws + OFF_WQ);
  u16* Wkb = (u16*)(ws + OFF_WK);
  u16* WvT = (u16*)(ws + OFF_WVT);
  u16* NT  = (u16*)(ws + OFF_NT);
  u16* Yb  = (u16*)(ws + OFF_Y);
  u16* VT  = (u16*)(ws + OFF_VT);
  float* S = (float*)(ws + OFF_S);

  int NB = 8;
  while (NB > 1 && OFF_S + (size_t)NB * T * T * 4 > ws_size) NB >>= 1;

  cvt_x<<<(B * T * D / 4 + 255) / 256, 256, 0, stream>>>((const float4*)x, xb, B * T * D / 4);
  cvt_x<<<(D * D / 4 + 255) / 256, 256, 0, stream>>>((const float4*)Wq, Wqb, D * D / 4);
  cvt_x<<<(D * D / 4 + 255) / 256, 256, 0, stream>>>((const float4*)Wk, Wkb, D * D / 4);
  cvt_w<<<dim3(16, 16), 256, 0, stream>>>(Wv, WvT);

  // N^T[d',d] = sum_e Wk[d',e] Wq[d,e]   (8x8 tiles)
  gemm_rect<u16><<<dim3(64, 1), 256, 0, stream>>>(
      Wkb, D, 0L, Wqb, D, 0L, NT, D, 0L, D, 3, 3);
  // Y = x @ N  (Gx=8 col-tiles, Gy=128 row-tiles)
  gemm_rect<u16><<<dim3(1024, 1), 256, 0, stream>>>(
      xb, D, 0L, NT, D, 0L, Yb, D, 0L, D, 3, 7);
  // V^T = Wv^T @ x^T  (Gx=128, Gy=8)
  gemm_rect<u16><<<dim3(1024, 1), 256, 0, stream>>>(
      WvT, D, 0L, xb, D, 0L, VT, B * T, 0L, D, 7, 7);

  for (int b0 = 0; b0 < B; b0 += NB) {
    gemm_tri<<<dim3(136, NB), 256, 0, stream>>>(
        Yb + (long)b0 * T * D, D, (long)T * D,
        xb + (long)b0 * T * D, D, (long)T * D,
        S, T, (long)T * T, D);
    softmax_causal<<<NB * T, 256, 0, stream>>>(S, 0.03125f);
    gemm_opv<<<dim3(128, NB), 256, 0, stream>>>(
        (const u16*)S, 2 * T, (long)T * 2 * T,
        VT + (long)b0 * T, B * T, (long)T,
        out + (long)b0 * T * D, D, (long)T * D);
  }
}

// Round 4
// 370.165 us; speedup vs baseline: 1.3190x; 1.0610x over previous
//
#include <hip/hip_runtime.h>

using u16 = unsigned short;
typedef __bf16 bf16x8 __attribute__((ext_vector_type(8)));
typedef unsigned short u16x8 __attribute__((ext_vector_type(8)));
typedef float floatx4 __attribute__((ext_vector_type(4)));

__device__ __forceinline__ u16 f2bf(float f) {
  union { float f; unsigned u; } c; c.f = f;
  unsigned u = c.u;
  u += 0x7fffu + ((u >> 16) & 1u);   // round-to-nearest-even
  return (u16)(u >> 16);
}
__device__ __forceinline__ float bf2f(u16 h) {
  union { unsigned u; float f; } c; c.u = ((unsigned)h) << 16; return c.f;
}

__device__ __forceinline__ void st_out(float* p, float v) { *p = v; }
__device__ __forceinline__ void st_out(u16* p, float v) { *p = f2bf(v); }

__device__ __forceinline__ void load16(const u16* g, u16* l) {
  __builtin_amdgcn_global_load_lds(
      (const __attribute__((address_space(1))) void*)g,
      (__attribute__((address_space(3))) void*)l, 16, 0, 0);
}

#define TILE 128
#define BK 64

// Core 128x128 tile GEMM, BK=64: C = A[M,K] @ Bt[N,K]^T, bf16 in, fp32 acc.
// LDS: row r's 8 16B-chunks XOR-permuted (slot = m ^ (r&7)) -> 0 bank conflicts (R3).
template<typename OutT>
__device__ __forceinline__ void gemm_core(
    const u16* __restrict__ A, int lda, long sA,
    const u16* __restrict__ Bt, int ldb, long sB,
    OutT* __restrict__ C, int ldc, long sC,
    int kmax, int bx, int by, int bz, int tid)
{
  __shared__ u16 As[TILE * BK];
  __shared__ u16 Bs[TILE * BK];

  const u16* Ab = A + bz * sA + (long)by * TILE * lda;
  const u16* Bb = Bt + bz * sB + (long)bx * TILE * ldb;

  int lane = tid & 63;
  int wm = ((tid >> 7) & 1) * 64;
  int wn = ((tid >> 6) & 1) * 64;

  floatx4 acc[4][4] = {};
  int arow = wm + (lane & 15);
  int brow = wn + (lane & 15);
  int q = lane >> 4;

  for (int k0 = 0; k0 < kmax; k0 += BK) {
    __syncthreads();
#pragma unroll
    for (int h = 0; h < 4; h++) {
      int cc = tid + h * 256;
      int row = cc >> 3, gm = (cc & 7) ^ (row & 7);
      load16(Ab + (long)row * lda + k0 + gm * 8, &As[cc * 8]);
    }
#pragma unroll
    for (int h = 0; h < 4; h++) {
      int cc = tid + h * 256;
      int row = cc >> 3, gm = (cc & 7) ^ (row & 7);
      load16(Bb + (long)row * ldb + k0 + gm * 8, &Bs[cc * 8]);
    }
    __builtin_amdgcn_s_waitcnt(0);
    __syncthreads();

#pragma unroll
    for (int kp = 0; kp < 2; kp++) {
      bf16x8 a[4], b[4];
#pragma unroll
      for (int i = 0; i < 4; i++) {
        int r = arow + i * 16;
        a[i] = *(const bf16x8*)&As[(r * 8 + ((kp * 4 + q) ^ (r & 7))) * 8];
      }
#pragma unroll
      for (int j = 0; j < 4; j++) {
        int r = brow + j * 16;
        b[j] = *(const bf16x8*)&Bs[(r * 8 + ((kp * 4 + q) ^ (r & 7))) * 8];
      }
#pragma unroll
      for (int i = 0; i < 4; i++)
#pragma unroll
        for (int j = 0; j < 4; j++)
          acc[i][j] = __builtin_amdgcn_mfma_f32_16x16x32_bf16(a[i], b[j], acc[i][j], 0, 0, 0);
    }
  }

  // epilogue: C/D layout col=lane&15, row=(lane>>4)*4+reg  [m89-verified]
  OutT* Cb = C + bz * sC;
  int colbase = bx * TILE + wn + (lane & 15);
  int rowbase = by * TILE + wm + ((lane >> 4) << 2);
#pragma unroll
  for (int i = 0; i < 4; i++)
#pragma unroll
    for (int j = 0; j < 4; j++) {
      int col = colbase + j * 16;
#pragma unroll
      for (int r = 0; r < 4; r++)
        st_out(&Cb[(long)(rowbase + i * 16 + r) * ldc + col], acc[i][j][r]);
    }
}

// Small rectangular GEMM (used for NT), XCD-contiguous remap
template<typename OutT>
__global__ __launch_bounds__(256, 2)
void gemm_rect(const u16* __restrict__ A, int lda, long sA,
               const u16* __restrict__ Bt, int ldb, long sB,
               OutT* __restrict__ C, int ldc, long sC, int K,
               int l2gx, int nO8s)
{
  int L = blockIdx.x;
  int t = ((L & 7) << nO8s) | (L >> 3);
  int bx = t & ((1 << l2gx) - 1), by = t >> l2gx;
  gemm_core<OutT>(A, lda, sA, Bt, ldb, sB, C, ldc, sC, K, bx, by, blockIdx.y, threadIdx.x);
}

// Merged projections: L<1024 -> Y = xb @ NT^T ; L>=1024 -> VT = WvT @ xb^T
__global__ __launch_bounds__(256, 2)
void gemm_proj(const u16* __restrict__ xb, const u16* __restrict__ NT,
               const u16* __restrict__ WvT, u16* __restrict__ Yb,
               u16* __restrict__ VT)
{
  int L = blockIdx.x;
  bool h = (L >= 1024);
  int LL = h ? L - 1024 : L;
  int t = ((LL & 7) << 7) | (LL >> 3);
  int bx = h ? (t & 127) : (t & 7);
  int by = h ? (t >> 7) : (t >> 3);
  gemm_core<u16>(h ? WvT : xb, 1024, 0L,
                 h ? xb : NT, 1024, 0L,
                 h ? VT : Yb, h ? 16384 : 1024, 0L,
                 1024, bx, by, 0, threadIdx.x);
}

// Causal S = Y @ x^T -> bf16 scores (scale pre-folded into Wq). 136 tiles/batch,
// XCD-grouped (17 contiguous triangle slots per XCD).
__global__ __launch_bounds__(256, 2)
void gemm_tri(const u16* __restrict__ A, int lda, long sA,
              const u16* __restrict__ Bt, int ldb, long sB,
              u16* __restrict__ C, int ldc, long sC, int K)
{
  int tp = blockIdx.x;                       // 0..135
  int t = (tp & 7) * 17 + (tp >> 3);
  int r = (int)((sqrtf(8.f * t + 1.f) - 1.f) * 0.5f);
  while ((r + 1) * (r + 2) / 2 <= t) ++r;
  while (r * (r + 1) / 2 > t) --r;
  int c = t - r * (r + 1) / 2;
  gemm_core<u16>(A, lda, sA, Bt, ldb, sB, C, ldc, sC, K, c, r, blockIdx.y, threadIdx.x);
}

// O = P @ V via VT; causal K-trim. XCD j runs long row (15-j) FIRST, then row j
// (longest-first: short blocks fill the tail). P-strip reuse stays in one XCD.
__global__ __launch_bounds__(256, 2)
void gemm_opv(const u16* __restrict__ P, int lda, long sA,
              const u16* __restrict__ VT, int ldb, long sB,
              float* __restrict__ C, int ldc, long sC)
{
  int L = blockIdx.x;                        // 0..127
  int j = L & 7, s = L >> 3;
  int by = (s < 8) ? 15 - j : j;
  int bx = s & 7;
  gemm_core<float>(P, lda, sA, VT, ldb, sB, C, ldc, sC,
                   (by + 1) * TILE, bx, by, blockIdx.y, threadIdx.x);
}

// fp32 -> bf16 with scale, 4 elems/thread
__global__ __launch_bounds__(256)
void cvt_x(const float4* __restrict__ x, u16* __restrict__ o, int n4, float scale)
{
  int i = blockIdx.x * 256 + threadIdx.x;
  if (i >= n4) return;
  float4 v = x[i];
  ushort4 r;
  r.x = f2bf(v.x * scale); r.y = f2bf(v.y * scale);
  r.z = f2bf(v.z * scale); r.w = f2bf(v.w * scale);
  *(ushort4*)(o + (long)i * 4) = r;
}

// W (d_in x d_out) fp32 -> W^T (d_out x d_in) bf16, LDS tiled
__global__ __launch_bounds__(256)
void cvt_w(const float* __restrict__ W, u16* __restrict__ O)
{
  const int D = 1024;
  __shared__ float t[64][65];
  int tid = threadIdx.x;
  int c = tid & 63, r = tid >> 6;
  int e0 = blockIdx.x * 64, d0 = blockIdx.y * 64;
  for (int rr = r; rr < 64; rr += 4)
    t[rr][c] = W[(long)(d0 + rr) * D + e0 + c];
  __syncthreads();
  for (int rr = r; rr < 64; rr += 4)
    O[(long)(e0 + rr) * D + d0 + c] = f2bf(t[c][rr]);
}

// causal softmax over bf16 scores, in-place; one block per row, 8 elems/thread
// (scores are pre-scaled: 1/32 folded into Wq)
__global__ __launch_bounds__(256)
void softmax_bf16(u16* __restrict__ S)
{
  const int T = 2048;
  int row = blockIdx.x & (T - 1);
  u16* Prow = S + (long)blockIdx.x * T;    // (bi*T+row)*T
  int n = row + 1;
  int tid = threadIdx.x, lane = tid & 63, wid = tid >> 6;
  int i0 = tid * 8;

  u16x8 pv = *(const u16x8*)(Prow + i0);
  float v[8];
  float lmax = -3.0e38f;
#pragma unroll
  for (int j = 0; j < 8; j++) {
    v[j] = (i0 + j < n) ? bf2f(pv[j]) : -3.0e38f;
    lmax = fmaxf(lmax, v[j]);
  }
  __shared__ float red[8];
#pragma unroll
  for (int o = 32; o > 0; o >>= 1) lmax = fmaxf(lmax, __shfl_down(lmax, o, 64));
  if (lane == 0) red[wid] = lmax;
  __syncthreads();
  float m = fmaxf(fmaxf(red[0], red[1]), fmaxf(red[2], red[3]));

  float lsum = 0.f;
#pragma unroll
  for (int j = 0; j < 8; j++) {
    float e = (i0 + j < n) ? __expf(v[j] - m) : 0.f;
    v[j] = e;
    lsum += e;
  }
#pragma unroll
  for (int o = 32; o > 0; o >>= 1) lsum += __shfl_down(lsum, o, 64);
  if (lane == 0) red[4 + wid] = lsum;
  __syncthreads();
  float inv = 1.0f / (red[4] + red[5] + red[6] + red[7]);

  u16x8 w;
#pragma unroll
  for (int j = 0; j < 8; j++) w[j] = f2bf(v[j] * inv);
  *(u16x8*)(Prow + i0) = w;
}

extern "C" void kernel_launch(void* const* d_in, const int* in_sizes, int n_in,
                              void* d_out, int out_size, void* d_ws, size_t ws_size,
                              hipStream_t stream)
{
  const int B = 8, T = 2048, D = 1024;
  const float* x  = (const float*)d_in[0];
  const float* Wq = (const float*)d_in[1];
  const float* Wk = (const float*)d_in[2];
  const float* Wv = (const float*)d_in[3];
  float* out = (float*)d_out;
  char* ws = (char*)d_ws;

  // layout (MB): xb 0-32 | WvT 32-34 | NT 34-36 | Yb 36-68 (Wqb@36,Wkb@38 dead
  // after NT gemm) | VT 68-100 | S bf16 @100 (8 MB/batch)
  u16* xb  = (u16*)(ws);
  u16* WvT = (u16*)(ws + (32ul << 20));
  u16* NT  = (u16*)(ws + (34ul << 20));
  u16* Yb  = (u16*)(ws + (36ul << 20));
  u16* Wqb = Yb;                            // transient
  u16* Wkb = (u16*)(ws + (38ul << 20));     // transient
  u16* VT  = (u16*)(ws + (68ul << 20));
  u16* S   = (u16*)(ws + (100ul << 20));

  const size_t OFF_S = 100ul << 20;
  int NB = 8;
  while (NB > 1 && OFF_S + (size_t)NB * T * T * 2 > ws_size) NB >>= 1;

  cvt_x<<<(B * T * D / 4 + 255) / 256, 256, 0, stream>>>((const float4*)x, xb, B * T * D / 4, 1.0f);
  cvt_x<<<(D * D / 4 + 255) / 256, 256, 0, stream>>>((const float4*)Wq, Wqb, D * D / 4, 0.03125f);
  cvt_x<<<(D * D / 4 + 255) / 256, 256, 0, stream>>>((const float4*)Wk, Wkb, D * D / 4, 1.0f);
  cvt_w<<<dim3(16, 16), 256, 0, stream>>>(Wv, WvT);

  // NT[d',d] = sum_e Wk[d',e] Wq'[d,e]   (scale folded into Wq')
  gemm_rect<u16><<<dim3(64, 1), 256, 0, stream>>>(
      Wkb, D, 0L, Wqb, D, 0L, NT, D, 0L, D, 3, 3);
  // Y = xb @ NT^T  and  VT = WvT @ xb^T  in one dispatch
  gemm_proj<<<dim3(2048, 1), 256, 0, stream>>>(xb, NT, WvT, Yb, VT);

  for (int b0 = 0; b0 < B; b0 += NB) {
    gemm_tri<<<dim3(136, NB), 256, 0, stream>>>(
        Yb + (long)b0 * T * D, D, (long)T * D,
        xb + (long)b0 * T * D, D, (long)T * D,
        S, T, (long)T * T, D);
    softmax_bf16<<<NB * T, 256, 0, stream>>>(S);
    gemm_opv<<<dim3(128, NB), 256, 0, stream>>>(
        S, T, (long)T * T,
        VT + (long)b0 * T, B * T, (long)T,
        out + (long)b0 * T * D, D, (long)T * D);
  }
}